// Round 7
// baseline (21.726 us; speedup 1.0000x reference)
//
#include <hip/hip_runtime.h>

#define DIM 10
#define BATCH 65536

typedef _Float16 h2 __attribute__((ext_vector_type(2)));

#if defined(__has_builtin)
#  if __has_builtin(__builtin_amdgcn_fdot2)
#    define HAS_FDOT2 1
#  endif
#endif
#ifndef HAS_FDOT2
#  define HAS_FDOT2 0
#endif

// ---------------------------------------------------------------------------
// Kernel 1: row/col sums of each 10x10 element -> 20 transposed planes in ws.
// rc[(0..9)*BATCH + e]  = row sums, rc[(10..19)*BATCH + e] = col sums.
// 512 blocks x 256 thr; 128 elems/block; wave-private staging (no barrier);
// 2048 waves = 2 waves/SIMD -> staging of one wave overlaps compute of other.
// ---------------------------------------------------------------------------
__launch_bounds__(256, 2)
__global__ void rc_kernel(const float* __restrict__ x, float* __restrict__ rc) {
    __shared__ __align__(16) float xs[128 * 100];   // 51.2 KiB

    const int tid  = threadIdx.x;
    const int wave = tid >> 6;
    const int lane = tid & 63;
    const int l2   = lane >> 1;       // wave-local element [0,32)
    const int h    = lane & 1;        // 0 -> store rows, 1 -> store cols
    const size_t blk0 = (size_t)blockIdx.x * 128;

    // wave-private staging: 32 elems = 12800 B = 12 x 1KiB + 2 x 256B
    const float* gsrc = x + (blk0 + (size_t)wave * 32) * 100;
    float* lbase = xs + wave * 3200;
    #pragma unroll
    for (int c = 0; c < 12; ++c) {
        __builtin_amdgcn_global_load_lds(
            (const __attribute__((address_space(1))) void*)(gsrc + c * 256 + lane * 4),
            (__attribute__((address_space(3))) void*)(lbase + c * 256),
            16, 0, 0);
    }
    #pragma unroll
    for (int c = 0; c < 2; ++c) {
        __builtin_amdgcn_global_load_lds(
            (const __attribute__((address_space(1))) void*)(gsrc + 3072 + c * 64 + lane),
            (__attribute__((address_space(3))) void*)(lbase + 3072 + c * 64),
            4, 0, 0);
    }
    asm volatile("s_waitcnt vmcnt(0)" ::: "memory");

    // both lanes of a pair read the same element (pair-broadcast is free)
    const float4* eb = reinterpret_cast<const float4*>(lbase + l2 * 100);
    float row[DIM], col[DIM];
    #pragma unroll
    for (int i = 0; i < DIM; ++i) { row[i] = 0.f; col[i] = 0.f; }
    #pragma unroll
    for (int t = 0; t < 25; ++t) {
        const float4 v = eb[t];
        const int e0 = t * 4;
        row[(e0 + 0) / DIM] += v.x; col[(e0 + 0) % DIM] += v.x;
        row[(e0 + 1) / DIM] += v.y; col[(e0 + 1) % DIM] += v.y;
        row[(e0 + 2) / DIM] += v.z; col[(e0 + 2) % DIM] += v.z;
        row[(e0 + 3) / DIM] += v.w; col[(e0 + 3) % DIM] += v.w;
    }

    // h=0 lane stores the 10 row planes, h=1 lane the 10 col planes.
    const size_t eg = blk0 + (size_t)wave * 32 + l2;
    #pragma unroll
    for (int i = 0; i < DIM; ++i) {
        const float v = h ? col[i] : row[i];
        rc[(size_t)(h * 10 + i) * BATCH + eg] = v;
    }
}

// ---------------------------------------------------------------------------
// Kernel 2: conv + head from the rc planes. 1 elem/thread, 20 coalesced
// dword loads, no LDS, f16-dot2 conv core.
// ---------------------------------------------------------------------------
__launch_bounds__(256, 1)
__global__ void conv_kernel(const float* __restrict__ rc,
                            const float* __restrict__ w1,
                            const float* __restrict__ b1,
                            const float* __restrict__ w2,
                            const float* __restrict__ b2,
                            const float* __restrict__ fc1_w,
                            const float* __restrict__ fc1_b,
                            const float* __restrict__ fc2_w,
                            const float* __restrict__ fc2_b,
                            float* __restrict__ out) {
    const size_t e = (size_t)blockIdx.x * 256 + threadIdx.x;

    // issue all 20 coalesced loads up front; weight setup hides their latency
    float row[DIM], col[DIM];
    #pragma unroll
    for (int i = 0; i < DIM; ++i) row[i] = rc[(size_t)i * BATCH + e];
    #pragma unroll
    for (int j = 0; j < DIM; ++j) col[j] = rc[(size_t)(10 + j) * BATCH + e];

    h2 W1h[5], B1h[5], W2h[5][9];
    #pragma unroll
    for (int cp = 0; cp < 5; ++cp) {
        W1h[cp][0] = (_Float16)w1[2 * cp];     W1h[cp][1] = (_Float16)w1[2 * cp + 1];
        B1h[cp][0] = (_Float16)b1[2 * cp];     B1h[cp][1] = (_Float16)b1[2 * cp + 1];
        #pragma unroll
        for (int k = 0; k < 9; ++k) {
            W2h[cp][k][0] = (_Float16)w2[(2 * cp) * 9 + k];
            W2h[cp][k][1] = (_Float16)w2[(2 * cp + 1) * 9 + k];
        }
    }
    const float B2 = b2[0];

    float acc[DIM][DIM];
    #pragma unroll
    for (int i = 0; i < DIM; ++i)
        #pragma unroll
        for (int j = 0; j < DIM; ++j) acc[i][j] = 0.f;

    const h2 zero_h2 = (h2){(_Float16)0, (_Float16)0};

    #pragma unroll
    for (int p = 0; p < DIM; ++p) {
        #pragma unroll
        for (int q = 0; q <= p; ++q) {
            const float ev = row[p] + col[q];
            float s[9];
            #pragma unroll
            for (int k = 0; k < 9; ++k) s[k] = 0.f;
#if HAS_FDOT2
            const _Float16 eh = (_Float16)ev;
            const h2 e2 = (h2){eh, eh};
            #pragma unroll
            for (int cp = 0; cp < 5; ++cp) {
                h2 g = __builtin_elementwise_fma(W1h[cp], e2, B1h[cp]);
                g = __builtin_elementwise_max(g, zero_h2);
                #pragma unroll
                for (int k = 0; k < 9; ++k)
                    s[k] = __builtin_amdgcn_fdot2(g, W2h[cp][k], s[k], false);
            }
#else
            #pragma unroll
            for (int cp = 0; cp < 5; ++cp) {
                const float g0 = fmaxf(fmaf((float)W1h[cp][0], ev, (float)B1h[cp][0]), 0.f);
                const float g1 = fmaxf(fmaf((float)W1h[cp][1], ev, (float)B1h[cp][1]), 0.f);
                #pragma unroll
                for (int k = 0; k < 9; ++k) {
                    s[k] = fmaf(g0, (float)W2h[cp][k][0], s[k]);
                    s[k] = fmaf(g1, (float)W2h[cp][k][1], s[k]);
                }
            }
#endif
            // scatter: source (p,q) feeds out (p+1-a, q+1-bb), tap k=a*3+bb
            #pragma unroll
            for (int a = 0; a < 3; ++a) {
                const int i = p + 1 - a;
                if (i < 0 || i >= DIM) continue;          // folds at compile time
                #pragma unroll
                for (int bb = 0; bb < 3; ++bb) {
                    const int j = q + 1 - bb;
                    if (j < 0 || j >= DIM) continue;
                    acc[i][j] += s[a * 3 + bb];
                }
            }
        }
    }

    float vsum[DIM];
    #pragma unroll
    for (int k = 0; k < DIM; ++k) vsum[k] = 0.f;
    #pragma unroll
    for (int i = 0; i < DIM; ++i) {
        #pragma unroll
        for (int j = 0; j < DIM; ++j) {
            const float m = fmaxf(acc[i][j] + B2, 0.f);
            vsum[i] += m;
            vsum[j] += m;
        }
    }

    float hid[4];
    #pragma unroll
    for (int t = 0; t < 4; ++t) {
        float a = fc1_b[t];
        #pragma unroll
        for (int k = 0; k < DIM; ++k) a = fmaf(vsum[k], fc1_w[t * DIM + k], a);
        hid[t] = fmaxf(a, 0.f);
    }
    float o0 = fc2_b[0], o1 = fc2_b[1];
    #pragma unroll
    for (int t = 0; t < 4; ++t) {
        o0 = fmaf(hid[t], fc2_w[t], o0);
        o1 = fmaf(hid[t], fc2_w[4 + t], o1);
    }
    reinterpret_cast<float2*>(out)[e] = make_float2(o0, o1);
}

// ---------------------------------------------------------------------------
// Fallback: R6 single fused kernel (used only if ws_size is too small).
// ---------------------------------------------------------------------------
__launch_bounds__(256, 1)
__global__ void fused_kernel(const float* __restrict__ x,
                             const float* __restrict__ w1,
                             const float* __restrict__ b1,
                             const float* __restrict__ w2,
                             const float* __restrict__ b2,
                             const float* __restrict__ fc1_w,
                             const float* __restrict__ fc1_b,
                             const float* __restrict__ fc2_w,
                             const float* __restrict__ fc2_b,
                             float* __restrict__ out) {
    __shared__ __align__(16) float xs[256 * DIM * DIM];

    const int tid  = threadIdx.x;
    const int wave = tid >> 6;
    const int lane = tid & 63;
    const size_t blk0 = (size_t)blockIdx.x * 256;

    const float* gbase = x + (blk0 + (size_t)wave * 64) * (DIM * DIM);
    float* lbase = xs + wave * 64 * (DIM * DIM);
    #pragma unroll
    for (int c = 0; c < 25; ++c) {
        __builtin_amdgcn_global_load_lds(
            (const __attribute__((address_space(1))) void*)(gbase + c * 256 + lane * 4),
            (__attribute__((address_space(3))) void*)(lbase + c * 256),
            16, 0, 0);
    }

    h2 W1h[5], B1h[5], W2h[5][9];
    #pragma unroll
    for (int cp = 0; cp < 5; ++cp) {
        W1h[cp][0] = (_Float16)w1[2 * cp];     W1h[cp][1] = (_Float16)w1[2 * cp + 1];
        B1h[cp][0] = (_Float16)b1[2 * cp];     B1h[cp][1] = (_Float16)b1[2 * cp + 1];
        #pragma unroll
        for (int k = 0; k < 9; ++k) {
            W2h[cp][k][0] = (_Float16)w2[(2 * cp) * 9 + k];
            W2h[cp][k][1] = (_Float16)w2[(2 * cp + 1) * 9 + k];
        }
    }
    const float B2 = b2[0];

    asm volatile("s_waitcnt vmcnt(0)" ::: "memory");

    float row[DIM], col[DIM];
    #pragma unroll
    for (int i = 0; i < DIM; ++i) { row[i] = 0.f; col[i] = 0.f; }
    const float4* xb = reinterpret_cast<const float4*>(xs + tid * (DIM * DIM));
    #pragma unroll
    for (int t = 0; t < 25; ++t) {
        const float4 v = xb[t];
        const int e0 = t * 4;
        row[(e0 + 0) / DIM] += v.x; col[(e0 + 0) % DIM] += v.x;
        row[(e0 + 1) / DIM] += v.y; col[(e0 + 1) % DIM] += v.y;
        row[(e0 + 2) / DIM] += v.z; col[(e0 + 2) % DIM] += v.z;
        row[(e0 + 3) / DIM] += v.w; col[(e0 + 3) % DIM] += v.w;
    }

    float acc[DIM][DIM];
    #pragma unroll
    for (int i = 0; i < DIM; ++i)
        #pragma unroll
        for (int j = 0; j < DIM; ++j) acc[i][j] = 0.f;

    const h2 zero_h2 = (h2){(_Float16)0, (_Float16)0};

    #pragma unroll
    for (int p = 0; p < DIM; ++p) {
        #pragma unroll
        for (int q = 0; q <= p; ++q) {
            const float ev = row[p] + col[q];
            float s[9];
            #pragma unroll
            for (int k = 0; k < 9; ++k) s[k] = 0.f;
#if HAS_FDOT2
            const _Float16 eh = (_Float16)ev;
            const h2 e2 = (h2){eh, eh};
            #pragma unroll
            for (int cp = 0; cp < 5; ++cp) {
                h2 g = __builtin_elementwise_fma(W1h[cp], e2, B1h[cp]);
                g = __builtin_elementwise_max(g, zero_h2);
                #pragma unroll
                for (int k = 0; k < 9; ++k)
                    s[k] = __builtin_amdgcn_fdot2(g, W2h[cp][k], s[k], false);
            }
#else
            #pragma unroll
            for (int cp = 0; cp < 5; ++cp) {
                const float g0 = fmaxf(fmaf((float)W1h[cp][0], ev, (float)B1h[cp][0]), 0.f);
                const float g1 = fmaxf(fmaf((float)W1h[cp][1], ev, (float)B1h[cp][1]), 0.f);
                #pragma unroll
                for (int k = 0; k < 9; ++k) {
                    s[k] = fmaf(g0, (float)W2h[cp][k][0], s[k]);
                    s[k] = fmaf(g1, (float)W2h[cp][k][1], s[k]);
                }
            }
#endif
            #pragma unroll
            for (int a = 0; a < 3; ++a) {
                const int i = p + 1 - a;
                if (i < 0 || i >= DIM) continue;
                #pragma unroll
                for (int bb = 0; bb < 3; ++bb) {
                    const int j = q + 1 - bb;
                    if (j < 0 || j >= DIM) continue;
                    acc[i][j] += s[a * 3 + bb];
                }
            }
        }
    }

    float vsum[DIM];
    #pragma unroll
    for (int k = 0; k < DIM; ++k) vsum[k] = 0.f;
    #pragma unroll
    for (int i = 0; i < DIM; ++i) {
        #pragma unroll
        for (int j = 0; j < DIM; ++j) {
            const float m = fmaxf(acc[i][j] + B2, 0.f);
            vsum[i] += m;
            vsum[j] += m;
        }
    }

    float hid[4];
    #pragma unroll
    for (int t = 0; t < 4; ++t) {
        float a = fc1_b[t];
        #pragma unroll
        for (int k = 0; k < DIM; ++k) a = fmaf(vsum[k], fc1_w[t * DIM + k], a);
        hid[t] = fmaxf(a, 0.f);
    }
    float o0 = fc2_b[0], o1 = fc2_b[1];
    #pragma unroll
    for (int t = 0; t < 4; ++t) {
        o0 = fmaf(hid[t], fc2_w[t], o0);
        o1 = fmaf(hid[t], fc2_w[4 + t], o1);
    }
    reinterpret_cast<float2*>(out)[blk0 + tid] = make_float2(o0, o1);
}

extern "C" void kernel_launch(void* const* d_in, const int* in_sizes, int n_in,
                              void* d_out, int out_size, void* d_ws, size_t ws_size,
                              hipStream_t stream) {
    const float* x     = (const float*)d_in[0];
    const float* w1    = (const float*)d_in[1];
    const float* b1    = (const float*)d_in[2];
    const float* w2    = (const float*)d_in[3];
    const float* b2    = (const float*)d_in[4];
    const float* fc1_w = (const float*)d_in[5];
    const float* fc1_b = (const float*)d_in[6];
    const float* fc2_w = (const float*)d_in[7];
    const float* fc2_b = (const float*)d_in[8];
    float* out = (float*)d_out;

    const size_t rc_bytes = (size_t)20 * BATCH * sizeof(float);  // 5.24 MB
    if (ws_size >= rc_bytes) {
        float* rc = (float*)d_ws;
        rc_kernel<<<512, 256, 0, stream>>>(x, rc);
        conv_kernel<<<BATCH / 256, 256, 0, stream>>>(rc, w1, b1, w2, b2,
                                                     fc1_w, fc1_b, fc2_w, fc2_b,
                                                     out);
    } else {
        fused_kernel<<<BATCH / 256, 256, 0, stream>>>(x, w1, b1, w2, b2,
                                                      fc1_w, fc1_b, fc2_w, fc2_b,
                                                      out);
    }
}

// Round 8
// 16.642 us; speedup vs baseline: 1.3055x; 1.3055x over previous
//
#include <hip/hip_runtime.h>

#define DIM 10
#define BATCH 65536

typedef _Float16 h2 __attribute__((ext_vector_type(2)));

#if defined(__has_builtin)
#  if __has_builtin(__builtin_amdgcn_fdot2)
#    define HAS_FDOT2 1
#  endif
#endif
#ifndef HAS_FDOT2
#  define HAS_FDOT2 0
#endif

// Single fused kernel, NO LDS, NO barrier, NO vmcnt(0) drain:
// - 25 per-lane float4 loads issued at the very top (wave footprint is a
//   dense 25.6 KB -> fits L1, every fetched line fully consumed; compiler
//   inserts fine-grained vmcnt(N) so row/col math overlaps in-flight loads)
// - f16 weight setup (~200 uniform ops) runs under the load latency
// - conv core on the f16 pipe: 45 v_dot2_f32_f16 per pixel
__launch_bounds__(256, 1)
__global__ void net_kernel(const float* __restrict__ x,
                           const float* __restrict__ w1,
                           const float* __restrict__ b1,
                           const float* __restrict__ w2,
                           const float* __restrict__ b2,
                           const float* __restrict__ fc1_w,
                           const float* __restrict__ fc1_b,
                           const float* __restrict__ fc2_w,
                           const float* __restrict__ fc2_b,
                           float* __restrict__ out) {
    const int tid = threadIdx.x;
    const size_t e = (size_t)blockIdx.x * 256 + tid;

    // ---- issue all x loads FIRST (latency hides under weight setup) ----
    const float4* xb = reinterpret_cast<const float4*>(x + e * (DIM * DIM));
    float4 xv[25];
    #pragma unroll
    for (int t = 0; t < 25; ++t) xv[t] = xb[t];

    // ---- weights -> packed f16 (uniform scalar loads + cvt, ~200 ops) ----
    h2 W1h[5], B1h[5], W2h[5][9];
    #pragma unroll
    for (int cp = 0; cp < 5; ++cp) {
        W1h[cp][0] = (_Float16)w1[2 * cp];     W1h[cp][1] = (_Float16)w1[2 * cp + 1];
        B1h[cp][0] = (_Float16)b1[2 * cp];     B1h[cp][1] = (_Float16)b1[2 * cp + 1];
        #pragma unroll
        for (int k = 0; k < 9; ++k) {
            W2h[cp][k][0] = (_Float16)w2[(2 * cp) * 9 + k];
            W2h[cp][k][1] = (_Float16)w2[(2 * cp + 1) * 9 + k];
        }
    }
    const float B2 = b2[0];

    // ---- row/col sums (compiler interleaves with remaining in-flight loads) ----
    float row[DIM], col[DIM];
    #pragma unroll
    for (int i = 0; i < DIM; ++i) { row[i] = 0.f; col[i] = 0.f; }
    #pragma unroll
    for (int t = 0; t < 25; ++t) {
        const float4 v = xv[t];
        const int e0 = t * 4;
        row[(e0 + 0) / DIM] += v.x; col[(e0 + 0) % DIM] += v.x;
        row[(e0 + 1) / DIM] += v.y; col[(e0 + 1) % DIM] += v.y;
        row[(e0 + 2) / DIM] += v.z; col[(e0 + 2) % DIM] += v.z;
        row[(e0 + 3) / DIM] += v.w; col[(e0 + 3) % DIM] += v.w;
    }

    // ---- conv: 55 lower-triangle pixels, f16 dot2 core ----
    float acc[DIM][DIM];
    #pragma unroll
    for (int i = 0; i < DIM; ++i)
        #pragma unroll
        for (int j = 0; j < DIM; ++j) acc[i][j] = 0.f;

    const h2 zero_h2 = (h2){(_Float16)0, (_Float16)0};

    #pragma unroll
    for (int p = 0; p < DIM; ++p) {
        #pragma unroll
        for (int q = 0; q <= p; ++q) {
            const float ev = row[p] + col[q];
            float s[9];
            #pragma unroll
            for (int k = 0; k < 9; ++k) s[k] = 0.f;
#if HAS_FDOT2
            const _Float16 eh = (_Float16)ev;
            const h2 e2 = (h2){eh, eh};
            #pragma unroll
            for (int cp = 0; cp < 5; ++cp) {
                h2 g = __builtin_elementwise_fma(W1h[cp], e2, B1h[cp]);
                g = __builtin_elementwise_max(g, zero_h2);
                #pragma unroll
                for (int k = 0; k < 9; ++k)
                    s[k] = __builtin_amdgcn_fdot2(g, W2h[cp][k], s[k], false);
            }
#else
            #pragma unroll
            for (int cp = 0; cp < 5; ++cp) {
                const float g0 = fmaxf(fmaf((float)W1h[cp][0], ev, (float)B1h[cp][0]), 0.f);
                const float g1 = fmaxf(fmaf((float)W1h[cp][1], ev, (float)B1h[cp][1]), 0.f);
                #pragma unroll
                for (int k = 0; k < 9; ++k) {
                    s[k] = fmaf(g0, (float)W2h[cp][k][0], s[k]);
                    s[k] = fmaf(g1, (float)W2h[cp][k][1], s[k]);
                }
            }
#endif
            // scatter: source (p,q) feeds out (p+1-a, q+1-bb), tap k=a*3+bb
            #pragma unroll
            for (int a = 0; a < 3; ++a) {
                const int i = p + 1 - a;
                if (i < 0 || i >= DIM) continue;          // folds at compile time
                #pragma unroll
                for (int bb = 0; bb < 3; ++bb) {
                    const int j = q + 1 - bb;
                    if (j < 0 || j >= DIM) continue;
                    acc[i][j] += s[a * 3 + bb];
                }
            }
        }
    }

    // ---- m = relu(acc + b2); v[k] = row-sum + col-sum ----
    float vsum[DIM];
    #pragma unroll
    for (int k = 0; k < DIM; ++k) vsum[k] = 0.f;
    #pragma unroll
    for (int i = 0; i < DIM; ++i) {
        #pragma unroll
        for (int j = 0; j < DIM; ++j) {
            const float m = fmaxf(acc[i][j] + B2, 0.f);
            vsum[i] += m;
            vsum[j] += m;
        }
    }

    // ---- FC head ----
    float hid[4];
    #pragma unroll
    for (int t = 0; t < 4; ++t) {
        float a = fc1_b[t];
        #pragma unroll
        for (int k = 0; k < DIM; ++k) a = fmaf(vsum[k], fc1_w[t * DIM + k], a);
        hid[t] = fmaxf(a, 0.f);
    }
    float o0 = fc2_b[0], o1 = fc2_b[1];
    #pragma unroll
    for (int t = 0; t < 4; ++t) {
        o0 = fmaf(hid[t], fc2_w[t], o0);
        o1 = fmaf(hid[t], fc2_w[4 + t], o1);
    }
    reinterpret_cast<float2*>(out)[e] = make_float2(o0, o1);
}

extern "C" void kernel_launch(void* const* d_in, const int* in_sizes, int n_in,
                              void* d_out, int out_size, void* d_ws, size_t ws_size,
                              hipStream_t stream) {
    const float* x     = (const float*)d_in[0];
    const float* w1    = (const float*)d_in[1];
    const float* b1    = (const float*)d_in[2];
    const float* w2    = (const float*)d_in[3];
    const float* b2    = (const float*)d_in[4];
    const float* fc1_w = (const float*)d_in[5];
    const float* fc1_b = (const float*)d_in[6];
    const float* fc2_w = (const float*)d_in[7];
    const float* fc2_b = (const float*)d_in[8];
    float* out = (float*)d_out;

    const int block = 256;
    const int grid = BATCH / block;   // 256 blocks, 1 per CU
    net_kernel<<<grid, block, 0, stream>>>(x, w1, b1, w2, b2, fc1_w, fc1_b,
                                           fc2_w, fc2_b, out);
}

// Round 9
// 14.386 us; speedup vs baseline: 1.5102x; 1.1568x over previous
//
#include <hip/hip_runtime.h>

#define DIM 10
#define BATCH 65536

typedef _Float16 h2 __attribute__((ext_vector_type(2)));

#if defined(__has_builtin)
#  if __has_builtin(__builtin_amdgcn_fdot2)
#    define HAS_FDOT2 1
#  endif
#endif
#ifndef HAS_FDOT2
#  define HAS_FDOT2 0
#endif

// R6 skeleton (wave-private global_load_lds staging, no barrier) with a
// direct-accumulate conv: for each lower-triangle source pixel (p,q) and each
// VALID tap (a,bb) -> output (p+1-a, q+1-bb), run a 5-deep fdot2 chain
// straight into acc[i][j].  No s[9] temp, no s-init, no scatter adds, and
// invalid taps (out-of-bounds outputs) cost nothing.  b2 is folded into the
// acc initializer.
__launch_bounds__(256, 1)
__global__ void net_kernel(const float* __restrict__ x,
                           const float* __restrict__ w1,
                           const float* __restrict__ b1,
                           const float* __restrict__ w2,
                           const float* __restrict__ b2,
                           const float* __restrict__ fc1_w,
                           const float* __restrict__ fc1_b,
                           const float* __restrict__ fc2_w,
                           const float* __restrict__ fc2_b,
                           float* __restrict__ out) {
    __shared__ __align__(16) float xs[256 * DIM * DIM];

    const int tid  = threadIdx.x;
    const int wave = tid >> 6;
    const int lane = tid & 63;
    const size_t blk0 = (size_t)blockIdx.x * 256;

    // ---- Phase 1: wave-private coalesced staging (25 x 1 KiB per wave) ----
    const float* gbase = x + (blk0 + (size_t)wave * 64) * (DIM * DIM);
    float* lbase = xs + wave * 64 * (DIM * DIM);
    #pragma unroll
    for (int c = 0; c < 25; ++c) {
        __builtin_amdgcn_global_load_lds(
            (const __attribute__((address_space(1))) void*)(gbase + c * 256 + lane * 4),
            (__attribute__((address_space(3))) void*)(lbase + c * 256),
            16, 0, 0);
    }

    // ---- weights -> packed f16 (uniform loads; hides staging latency) ----
    h2 W1h[5], B1h[5], W2h[5][9];
    #pragma unroll
    for (int cp = 0; cp < 5; ++cp) {
        W1h[cp][0] = (_Float16)w1[2 * cp];     W1h[cp][1] = (_Float16)w1[2 * cp + 1];
        B1h[cp][0] = (_Float16)b1[2 * cp];     B1h[cp][1] = (_Float16)b1[2 * cp + 1];
        #pragma unroll
        for (int k = 0; k < 9; ++k) {
            W2h[cp][k][0] = (_Float16)w2[(2 * cp) * 9 + k];
            W2h[cp][k][1] = (_Float16)w2[(2 * cp + 1) * 9 + k];
        }
    }
    const float B2 = b2[0];

    // wave-level wait for our own 25 chunks (no block barrier needed)
    asm volatile("s_waitcnt vmcnt(0)" ::: "memory");

    // ---- Phase 2: per-thread row/col sums from own LDS row ----
    float row[DIM], col[DIM];
    #pragma unroll
    for (int i = 0; i < DIM; ++i) { row[i] = 0.f; col[i] = 0.f; }
    const float4* xb = reinterpret_cast<const float4*>(xs + tid * (DIM * DIM));
    #pragma unroll
    for (int t = 0; t < 25; ++t) {
        const float4 v = xb[t];
        const int e0 = t * 4;
        row[(e0 + 0) / DIM] += v.x; col[(e0 + 0) % DIM] += v.x;
        row[(e0 + 1) / DIM] += v.y; col[(e0 + 1) % DIM] += v.y;
        row[(e0 + 2) / DIM] += v.z; col[(e0 + 2) % DIM] += v.z;
        row[(e0 + 3) / DIM] += v.w; col[(e0 + 3) % DIM] += v.w;
    }

    // ---- Phase 3: conv, direct-accumulate (b2 folded into init) ----
    float acc[DIM][DIM];
    #pragma unroll
    for (int i = 0; i < DIM; ++i)
        #pragma unroll
        for (int j = 0; j < DIM; ++j) acc[i][j] = B2;

    const h2 zero_h2 = (h2){(_Float16)0, (_Float16)0};

    #pragma unroll
    for (int p = 0; p < DIM; ++p) {
        #pragma unroll
        for (int q = 0; q <= p; ++q) {
            const float ev = row[p] + col[q];
#if HAS_FDOT2
            const _Float16 eh = (_Float16)ev;
            const h2 e2 = (h2){eh, eh};
            h2 g[5];
            #pragma unroll
            for (int cp = 0; cp < 5; ++cp) {
                g[cp] = __builtin_elementwise_max(
                    __builtin_elementwise_fma(W1h[cp], e2, B1h[cp]), zero_h2);
            }
            // per VALID tap: 5-deep fdot2 chain straight into acc[i][j]
            #pragma unroll
            for (int a = 0; a < 3; ++a) {
                const int i = p + 1 - a;
                if (i < 0 || i >= DIM) continue;          // folds at compile time
                #pragma unroll
                for (int bb = 0; bb < 3; ++bb) {
                    const int j = q + 1 - bb;
                    if (j < 0 || j >= DIM) continue;
                    const int k = a * 3 + bb;
                    float t0 = acc[i][j];
                    #pragma unroll
                    for (int cp = 0; cp < 5; ++cp)
                        t0 = __builtin_amdgcn_fdot2(g[cp], W2h[cp][k], t0, false);
                    acc[i][j] = t0;
                }
            }
#else
            float gs[10];
            #pragma unroll
            for (int cp = 0; cp < 5; ++cp) {
                gs[2*cp]   = fmaxf(fmaf((float)W1h[cp][0], ev, (float)B1h[cp][0]), 0.f);
                gs[2*cp+1] = fmaxf(fmaf((float)W1h[cp][1], ev, (float)B1h[cp][1]), 0.f);
            }
            #pragma unroll
            for (int a = 0; a < 3; ++a) {
                const int i = p + 1 - a;
                if (i < 0 || i >= DIM) continue;
                #pragma unroll
                for (int bb = 0; bb < 3; ++bb) {
                    const int j = q + 1 - bb;
                    if (j < 0 || j >= DIM) continue;
                    const int k = a * 3 + bb;
                    float t0 = acc[i][j];
                    #pragma unroll
                    for (int cp = 0; cp < 5; ++cp) {
                        t0 = fmaf(gs[2*cp],   (float)W2h[cp][k][0], t0);
                        t0 = fmaf(gs[2*cp+1], (float)W2h[cp][k][1], t0);
                    }
                    acc[i][j] = t0;
                }
            }
#endif
        }
    }

    // ---- m = relu(acc) (b2 already folded); v[k] = row-sum + col-sum ----
    float vsum[DIM];
    #pragma unroll
    for (int k = 0; k < DIM; ++k) vsum[k] = 0.f;
    #pragma unroll
    for (int i = 0; i < DIM; ++i) {
        #pragma unroll
        for (int j = 0; j < DIM; ++j) {
            const float m = fmaxf(acc[i][j], 0.f);
            vsum[i] += m;
            vsum[j] += m;
        }
    }

    // ---- FC head ----
    float hid[4];
    #pragma unroll
    for (int t = 0; t < 4; ++t) {
        float a = fc1_b[t];
        #pragma unroll
        for (int k = 0; k < DIM; ++k) a = fmaf(vsum[k], fc1_w[t * DIM + k], a);
        hid[t] = fmaxf(a, 0.f);
    }
    float o0 = fc2_b[0], o1 = fc2_b[1];
    #pragma unroll
    for (int t = 0; t < 4; ++t) {
        o0 = fmaf(hid[t], fc2_w[t], o0);
        o1 = fmaf(hid[t], fc2_w[4 + t], o1);
    }
    reinterpret_cast<float2*>(out)[blk0 + tid] = make_float2(o0, o1);
}

extern "C" void kernel_launch(void* const* d_in, const int* in_sizes, int n_in,
                              void* d_out, int out_size, void* d_ws, size_t ws_size,
                              hipStream_t stream) {
    const float* x     = (const float*)d_in[0];
    const float* w1    = (const float*)d_in[1];
    const float* b1    = (const float*)d_in[2];
    const float* w2    = (const float*)d_in[3];
    const float* b2    = (const float*)d_in[4];
    const float* fc1_w = (const float*)d_in[5];
    const float* fc1_b = (const float*)d_in[6];
    const float* fc2_w = (const float*)d_in[7];
    const float* fc2_b = (const float*)d_in[8];
    float* out = (float*)d_out;

    const int block = 256;
    const int grid = BATCH / block;   // 256 blocks, 1 per CU
    net_kernel<<<grid, block, 0, stream>>>(x, w1, b1, w2, b2, fc1_w, fc1_b,
                                           fc2_w, fc2_b, out);
}

// Round 10
// 14.159 us; speedup vs baseline: 1.5344x; 1.0160x over previous
//
#include <hip/hip_runtime.h>

#define DIM 10
#define BATCH 65536

typedef _Float16 h2 __attribute__((ext_vector_type(2)));

#if defined(__has_builtin)
#  if __has_builtin(__builtin_amdgcn_fdot2)
#    define HAS_FDOT2 1
#  endif
#endif
#ifndef HAS_FDOT2
#  define HAS_FDOT2 0
#endif

// I$-amortization A/B: identical per-thread work to R9, but 1024 blocks x 64
// threads (1 wave/block, 4 blocks/CU) so four blocks share one cold I-cache
// fetch per CU (vs 1 block/CU paying the full ~24-32KB code fetch alone).
// LDS per block = one wave's staging quarter (25.6 KB); 4 blocks/CU fit.
__launch_bounds__(64, 1)
__global__ void net_kernel(const float* __restrict__ x,
                           const float* __restrict__ w1,
                           const float* __restrict__ b1,
                           const float* __restrict__ w2,
                           const float* __restrict__ b2,
                           const float* __restrict__ fc1_w,
                           const float* __restrict__ fc1_b,
                           const float* __restrict__ fc2_w,
                           const float* __restrict__ fc2_b,
                           float* __restrict__ out) {
    __shared__ __align__(16) float xs[64 * DIM * DIM];   // 25.6 KiB

    const int lane = threadIdx.x;                 // 64-thread block = 1 wave
    const size_t blk0 = (size_t)blockIdx.x * 64;

    // ---- Phase 1: wave-private coalesced staging (25 x 1 KiB) ----
    const float* gbase = x + blk0 * (DIM * DIM);
    #pragma unroll
    for (int c = 0; c < 25; ++c) {
        __builtin_amdgcn_global_load_lds(
            (const __attribute__((address_space(1))) void*)(gbase + c * 256 + lane * 4),
            (__attribute__((address_space(3))) void*)(xs + c * 256),
            16, 0, 0);
    }

    // ---- weights -> packed f16 (uniform loads; hides staging latency) ----
    h2 W1h[5], B1h[5], W2h[5][9];
    #pragma unroll
    for (int cp = 0; cp < 5; ++cp) {
        W1h[cp][0] = (_Float16)w1[2 * cp];     W1h[cp][1] = (_Float16)w1[2 * cp + 1];
        B1h[cp][0] = (_Float16)b1[2 * cp];     B1h[cp][1] = (_Float16)b1[2 * cp + 1];
        #pragma unroll
        for (int k = 0; k < 9; ++k) {
            W2h[cp][k][0] = (_Float16)w2[(2 * cp) * 9 + k];
            W2h[cp][k][1] = (_Float16)w2[(2 * cp + 1) * 9 + k];
        }
    }
    const float B2 = b2[0];

    // wave-level wait for our own 25 chunks (no block barrier needed)
    asm volatile("s_waitcnt vmcnt(0)" ::: "memory");

    // ---- Phase 2: per-thread row/col sums from own LDS row ----
    float row[DIM], col[DIM];
    #pragma unroll
    for (int i = 0; i < DIM; ++i) { row[i] = 0.f; col[i] = 0.f; }
    const float4* xb = reinterpret_cast<const float4*>(xs + lane * (DIM * DIM));
    #pragma unroll
    for (int t = 0; t < 25; ++t) {
        const float4 v = xb[t];
        const int e0 = t * 4;
        row[(e0 + 0) / DIM] += v.x; col[(e0 + 0) % DIM] += v.x;
        row[(e0 + 1) / DIM] += v.y; col[(e0 + 1) % DIM] += v.y;
        row[(e0 + 2) / DIM] += v.z; col[(e0 + 2) % DIM] += v.z;
        row[(e0 + 3) / DIM] += v.w; col[(e0 + 3) % DIM] += v.w;
    }

    // ---- Phase 3: conv, direct-accumulate (b2 folded into init) ----
    float acc[DIM][DIM];
    #pragma unroll
    for (int i = 0; i < DIM; ++i)
        #pragma unroll
        for (int j = 0; j < DIM; ++j) acc[i][j] = B2;

    const h2 zero_h2 = (h2){(_Float16)0, (_Float16)0};

    #pragma unroll
    for (int p = 0; p < DIM; ++p) {
        #pragma unroll
        for (int q = 0; q <= p; ++q) {
            const float ev = row[p] + col[q];
#if HAS_FDOT2
            const _Float16 eh = (_Float16)ev;
            const h2 e2 = (h2){eh, eh};
            h2 g[5];
            #pragma unroll
            for (int cp = 0; cp < 5; ++cp) {
                g[cp] = __builtin_elementwise_max(
                    __builtin_elementwise_fma(W1h[cp], e2, B1h[cp]), zero_h2);
            }
            // per VALID tap: 5-deep fdot2 chain straight into acc[i][j]
            #pragma unroll
            for (int a = 0; a < 3; ++a) {
                const int i = p + 1 - a;
                if (i < 0 || i >= DIM) continue;          // folds at compile time
                #pragma unroll
                for (int bb = 0; bb < 3; ++bb) {
                    const int j = q + 1 - bb;
                    if (j < 0 || j >= DIM) continue;
                    const int k = a * 3 + bb;
                    float t0 = acc[i][j];
                    #pragma unroll
                    for (int cp = 0; cp < 5; ++cp)
                        t0 = __builtin_amdgcn_fdot2(g[cp], W2h[cp][k], t0, false);
                    acc[i][j] = t0;
                }
            }
#else
            float gs[10];
            #pragma unroll
            for (int cp = 0; cp < 5; ++cp) {
                gs[2*cp]   = fmaxf(fmaf((float)W1h[cp][0], ev, (float)B1h[cp][0]), 0.f);
                gs[2*cp+1] = fmaxf(fmaf((float)W1h[cp][1], ev, (float)B1h[cp][1]), 0.f);
            }
            #pragma unroll
            for (int a = 0; a < 3; ++a) {
                const int i = p + 1 - a;
                if (i < 0 || i >= DIM) continue;
                #pragma unroll
                for (int bb = 0; bb < 3; ++bb) {
                    const int j = q + 1 - bb;
                    if (j < 0 || j >= DIM) continue;
                    const int k = a * 3 + bb;
                    float t0 = acc[i][j];
                    #pragma unroll
                    for (int cp = 0; cp < 5; ++cp) {
                        t0 = fmaf(gs[2*cp],   (float)W2h[cp][k][0], t0);
                        t0 = fmaf(gs[2*cp+1], (float)W2h[cp][k][1], t0);
                    }
                    acc[i][j] = t0;
                }
            }
#endif
        }
    }

    // ---- m = relu(acc) (b2 already folded); v[k] = row-sum + col-sum ----
    float vsum[DIM];
    #pragma unroll
    for (int k = 0; k < DIM; ++k) vsum[k] = 0.f;
    #pragma unroll
    for (int i = 0; i < DIM; ++i) {
        #pragma unroll
        for (int j = 0; j < DIM; ++j) {
            const float m = fmaxf(acc[i][j], 0.f);
            vsum[i] += m;
            vsum[j] += m;
        }
    }

    // ---- FC head ----
    float hid[4];
    #pragma unroll
    for (int t = 0; t < 4; ++t) {
        float a = fc1_b[t];
        #pragma unroll
        for (int k = 0; k < DIM; ++k) a = fmaf(vsum[k], fc1_w[t * DIM + k], a);
        hid[t] = fmaxf(a, 0.f);
    }
    float o0 = fc2_b[0], o1 = fc2_b[1];
    #pragma unroll
    for (int t = 0; t < 4; ++t) {
        o0 = fmaf(hid[t], fc2_w[t], o0);
        o1 = fmaf(hid[t], fc2_w[4 + t], o1);
    }
    reinterpret_cast<float2*>(out)[blk0 + lane] = make_float2(o0, o1);
}

extern "C" void kernel_launch(void* const* d_in, const int* in_sizes, int n_in,
                              void* d_out, int out_size, void* d_ws, size_t ws_size,
                              hipStream_t stream) {
    const float* x     = (const float*)d_in[0];
    const float* w1    = (const float*)d_in[1];
    const float* b1    = (const float*)d_in[2];
    const float* w2    = (const float*)d_in[3];
    const float* b2    = (const float*)d_in[4];
    const float* fc1_w = (const float*)d_in[5];
    const float* fc1_b = (const float*)d_in[6];
    const float* fc2_w = (const float*)d_in[7];
    const float* fc2_b = (const float*)d_in[8];
    float* out = (float*)d_out;

    const int block = 64;                 // 1 wave per block
    const int grid = BATCH / block;       // 1024 blocks -> 4 blocks/CU share I$
    net_kernel<<<grid, block, 0, stream>>>(x, w1, b1, w2, b2, fc1_w, fc1_b,
                                           fc2_w, fc2_b, out);
}